// Round 6
// baseline (19691.989 us; speedup 1.0000x reference)
//
#include <hip/hip_runtime.h>
#include <hip/hip_bf16.h>

typedef __hip_bfloat16 bf16;
typedef unsigned long long u64;
typedef unsigned int u32;
typedef unsigned short u16;
using short8 = __attribute__((ext_vector_type(8))) short;   // 8 bf16 MFMA A/B frag
using f32x4  = __attribute__((ext_vector_type(4))) float;   // MFMA C/D frag
using u32x4  = __attribute__((ext_vector_type(4))) u32;     // 16B chunk

#define T_STEPS 2048
#define IDIM    256
#define HDIM    512
#define NB0     32
#define NBLK    64
#define R0      8                 // h0 ring slots
#define R1      4                 // h1 ring slots
#define HS      16384             // bf16 per h slot: [32 blk][32 batch][16 units] = 32KB
#define LROW    528               // LDS row stride (bf16); 1056B == 8 dw mod 32 (conflict floor)

__device__ __forceinline__ float sigm(float x) { return 1.0f / (1.0f + __expf(-x)); }
__device__ __forceinline__ float tanh_f(float x) {
  x = fminf(fmaxf(x, -15.f), 15.f);
  float e = __expf(2.f * x);
  return (e - 1.f) / (e + 1.f);
}
__device__ __forceinline__ u16 bfbits(float f) {
  bf16 b = __float2bfloat16(f); u16 s; __builtin_memcpy(&s, &b, 2); return s;
}
__device__ __forceinline__ short8 cvt8(const float* __restrict__ p) {
  float4 lo = *(const float4*)(const void*)p;
  float4 hi = *(const float4*)(const void*)(p + 4);
  short8 r;
  r[0] = (short)bfbits(lo.x); r[1] = (short)bfbits(lo.y); r[2] = (short)bfbits(lo.z); r[3] = (short)bfbits(lo.w);
  r[4] = (short)bfbits(hi.x); r[5] = (short)bfbits(hi.y); r[6] = (short)bfbits(hi.z); r[7] = (short)bfbits(hi.w);
  return r;
}

// Coherent (L1/L2-bypassing, LLC point) accesses.
__device__ __forceinline__ u32 ldg4(const u32* p) {
  return __hip_atomic_load(p, __ATOMIC_RELAXED, __HIP_MEMORY_SCOPE_AGENT);
}
__device__ __forceinline__ void stg4(u32* p, u32 v) {
  __hip_atomic_store(p, v, __ATOMIC_RELAXED, __HIP_MEMORY_SCOPE_AGENT);
}
__device__ __forceinline__ u32x4 ldg16cv(const void* p) {   // 16B bypass load (async issue!)
  u32x4 r;
  asm volatile("global_load_dwordx4 %0, %1, off sc0 sc1" : "=v"(r) : "v"(p));
  return r;
}
__device__ __forceinline__ void stg16cv(void* p, u32x4 v) { // 16B bypass store
  asm volatile("global_store_dwordx4 %0, %1, off sc0 sc1" :: "v"(p), "v"(v) : "memory");
}

// Stage one 32KB block-major h slot -> LDS [batch][LROW]. 256 threads x 8 x 16B.
// Data is guaranteed committed (flag protocol) -> no tags, single sweep.
__device__ __forceinline__ void stage8(const bf16* __restrict__ src, bf16* dst, int tid) {
  u32x4 r0, r1, r2, r3, r4, r5, r6, r7;
  const char* s = (const char*)src;
  r0 = ldg16cv(s + (size_t)(tid + 0 * 256) * 16);
  r1 = ldg16cv(s + (size_t)(tid + 1 * 256) * 16);
  r2 = ldg16cv(s + (size_t)(tid + 2 * 256) * 16);
  r3 = ldg16cv(s + (size_t)(tid + 3 * 256) * 16);
  r4 = ldg16cv(s + (size_t)(tid + 4 * 256) * 16);
  r5 = ldg16cv(s + (size_t)(tid + 5 * 256) * 16);
  r6 = ldg16cv(s + (size_t)(tid + 6 * 256) * 16);
  r7 = ldg16cv(s + (size_t)(tid + 7 * 256) * 16);
  asm volatile("s_waitcnt vmcnt(0)" : "+v"(r0), "+v"(r1), "+v"(r2), "+v"(r3) :: "memory");
  asm volatile("s_waitcnt vmcnt(0)" : "+v"(r4), "+v"(r5), "+v"(r6), "+v"(r7) :: "memory");
  u32x4 rr[8] = {r0, r1, r2, r3, r4, r5, r6, r7};
#pragma unroll
  for (int i = 0; i < 8; i++) {
    int c = tid + i * 256;                 // chunk: blk = c>>6, r = c&63, m = r>>1, hf = r&1
    int blk = c >> 6, m = (c & 63) >> 1, hf = c & 1;
    *(u32x4*)(void*)(dst + m * LROW + blk * 16 + hf * 8) = rr[i];
  }
}

__device__ __forceinline__ int wave_min_i(int v) {
#pragma unroll
  for (int off = 32; off > 0; off >>= 1) {
    int o = __shfl_xor(v, off, 64);
    v = v < o ? v : o;
  }
  return v;
}

#define MFMA(a, b, c) __builtin_amdgcn_mfma_f32_16x16x32_bf16((a), (b), (c), 0, 0, 0)

__global__ void __launch_bounds__(256, 1) lstm_persistent(
    const float* __restrict__ x,
    const float* __restrict__ Wih0, const float* __restrict__ Whh0,
    const float* __restrict__ bih0, const float* __restrict__ bhh0,
    const float* __restrict__ Wih1, const float* __restrict__ Whh1,
    const float* __restrict__ bih1, const float* __restrict__ bhh1,
    const float* __restrict__ fcw, const float* __restrict__ fcb,
    float* __restrict__ out,
    u32* __restrict__ l0f,         // 32 x 128B l0 epoch flags
    u32* __restrict__ l1f,         // 32 x 128B l1 epoch flags
    u32* __restrict__ prog,        // 32 x 128B l1 read-progress lines
    bf16* __restrict__ h0ring,     // R0 x HS block-major
    bf16* __restrict__ h1ring) {   // R1 x HS block-major
  __shared__ __align__(16) bf16 lds_h0[32 * LROW];
  __shared__ __align__(16) bf16 lds_h1[32 * LROW];
  __shared__ __align__(16) bf16 hpack[32 * 16];    // [batch][16 units] block slice

  const int tid  = threadIdx.x;
  const int w    = tid >> 6, lane = tid & 63;
  const int q    = lane >> 4, m = lane & 15, q8 = q * 8;
  const int bx   = (int)blockIdx.x;
  const bool l0  = (bx < NB0);
  const int blk  = l0 ? bx : bx - NB0;
  const int jb   = blk * 16 + w * 4;
  const int unit = jb + (m >> 2), gate = m & 3;
  const int wrow = gate * HDIM + unit;
  const int ju   = jb + q;

  // ---- Preload weights (f32 -> bf16 A-frags) into VGPRs ----
  short8 A[32];
  f32x4 bias;
  if (l0) {
#pragma unroll
    for (int kc = 0; kc < 8; kc++)  A[kc]      = cvt8(Wih0 + wrow * IDIM + kc * 32 + q8);
#pragma unroll
    for (int kc = 0; kc < 16; kc++) A[8 + kc]  = cvt8(Whh0 + wrow * HDIM + kc * 32 + q8);
#pragma unroll
    for (int r = 0; r < 4; r++)
      bias[r] = bih0[r * HDIM + ju] + bhh0[r * HDIM + ju];
  } else {
#pragma unroll
    for (int kc = 0; kc < 16; kc++) A[kc]      = cvt8(Wih1 + wrow * HDIM + kc * 32 + q8);
#pragma unroll
    for (int kc = 0; kc < 16; kc++) A[16 + kc] = cvt8(Whh1 + wrow * HDIM + kc * 32 + q8);
#pragma unroll
    for (int r = 0; r < 4; r++)
      bias[r] = bih1[r * HDIM + ju] + bhh1[r * HDIM + ju];
  }

  float c_a = 0.f, c_b = 0.f;

  if (l0) {
    // prefetch xg[0]
    f32x4 an0 = bias, an1 = bias;
    {
      const float* xa = x + (size_t)m * (T_STEPS * IDIM) + q8;
      const float* xb = xa + (size_t)16 * (T_STEPS * IDIM);
#pragma unroll
      for (int kc = 0; kc < 8; kc++) {
        an0 = MFMA(A[kc], cvt8(xa + kc * 32), an0);
        an1 = MFMA(A[kc], cvt8(xb + kc * 32), an1);
      }
    }
    int est = 0;   // cached min l1 read-progress
    for (int p = 0; p < T_STEPS; ++p) {
      if (p > 0) {
        if (w == 0) {                                 // wave0 polls peer flags >= p
          u32 f;
          do { f = ldg4(l0f + (lane & 31) * 32); } while (!__all((int)(f >= (u32)p)));
        }
        __syncthreads();
        stage8(h0ring + ((p - 1) & (R0 - 1)) * HS, lds_h0, tid);   // h0[p-1]
        __syncthreads();
      }
      f32x4 a0 = an0, a1 = an1;                       // bias + Wih0 x[p]
      if (p > 0) {
#pragma unroll
        for (int kc = 0; kc < 16; kc++) {
          short8 b0 = *(const short8*)(const void*)(lds_h0 + m * LROW + kc * 32 + q8);
          short8 b1 = *(const short8*)(const void*)(lds_h0 + (m + 16) * LROW + kc * 32 + q8);
          a0 = MFMA(A[8 + kc], b0, a0);
          a1 = MFMA(A[8 + kc], b1, a1);
        }
      }
      float ia = sigm(a0[0]), fa = sigm(a0[1]), ga = tanh_f(a0[2]), oa = sigm(a0[3]);
      c_a = fa * c_a + ia * ga;
      float ib = sigm(a1[0]), fb = sigm(a1[1]), gb = tanh_f(a1[2]), ob = sigm(a1[3]);
      c_b = fb * c_b + ib * gb;
      hpack[m * 16 + (w * 4 + q)]        = __float2bfloat16(oa * tanh_f(c_a));
      hpack[(m + 16) * 16 + (w * 4 + q)] = __float2bfloat16(ob * tanh_f(c_b));
      __syncthreads();
      if (w == 0) {
        // flow control: slot p&7 holds h0[p-8]; l1 reader posts prog p-8+1 = p-7
        if (p >= R0) {
          int needed = p - R0 + 1;
          if (est < needed) {
            int mn;
            do {
              u32 pr = ldg4(prog + (lane & 31) * 32);
              mn = wave_min_i((int)pr);
            } while (mn < needed);
            est = mn;
          }
        }
        u32x4 d = *(const u32x4*)(const void*)(hpack + lane * 8);  // 16B of slice
        stg16cv(h0ring + (p & (R0 - 1)) * HS + blk * 512 + lane * 8, d);
        asm volatile("s_waitcnt vmcnt(0)" ::: "memory");           // drain to LLC
        if (lane == 0) stg4(l0f + blk * 32, (u32)(p + 1));         // publish epoch
      }
      if (p + 1 < T_STEPS) {                          // prefetch xg[p+1] (overlaps peers)
        an0 = bias; an1 = bias;
        const float* xa = x + (size_t)m * (T_STEPS * IDIM) + (size_t)(p + 1) * IDIM + q8;
        const float* xb = xa + (size_t)16 * (T_STEPS * IDIM);
#pragma unroll
        for (int kc = 0; kc < 8; kc++) {
          an0 = MFMA(A[kc], cvt8(xa + kc * 32), an0);
          an1 = MFMA(A[kc], cvt8(xb + kc * 32), an1);
        }
      }
    }

    // ---- FC epilogue: blocks 0..15 wait for l1 step 2047, then out = h1 @ fcw^T + fcb ----
    if (bx < 16) {
      if (w == 0) {
        u32 f;
        do { f = ldg4(l1f + (lane & 31) * 32); } while (!__all((int)(f >= (u32)T_STEPS)));
      }
      __syncthreads();
      stage8(h1ring + ((T_STEPS - 1) & (R1 - 1)) * HS, lds_h0, tid);
      __syncthreads();
      if (w == 0) {
        const int obase = bx * 16;
        f32x4 a0, a1;
#pragma unroll
        for (int r = 0; r < 4; r++) {
          float bb = fcb[obase + 4 * q + r];
          a0[r] = bb; a1[r] = bb;
        }
        const float* Ar = fcw + (size_t)(obase + m) * HDIM + q8;
#pragma unroll
        for (int kc = 0; kc < 16; kc++) {
          short8 af = cvt8(Ar + kc * 32);
          short8 b0 = *(const short8*)(const void*)(lds_h0 + m * LROW + kc * 32 + q8);
          short8 b1 = *(const short8*)(const void*)(lds_h0 + (m + 16) * LROW + kc * 32 + q8);
          a0 = MFMA(af, b0, a0);
          a1 = MFMA(af, b1, a1);
        }
#pragma unroll
        for (int r = 0; r < 4; r++) {
          out[m * 256 + obase + 4 * q + r]        = a0[r];
          out[(m + 16) * 256 + obase + 4 * q + r] = a1[r];
        }
      }
    }
  } else {
    // ---- layer 1 ----
    for (int p = 0; p < T_STEPS; ++p) {
      if (w == 0) {                                   // need h0[p] (l0f >= p+1), h1[p-1] (l1f >= p)
        for (;;) {
          u32 f;
          int pred;
          if (lane < 32) { f = ldg4(l0f + lane * 32);        pred = (f >= (u32)(p + 1)); }
          else           { f = (p > 0) ? ldg4(l1f + (lane - 32) * 32) : 0xffffffffu;
                           pred = (p == 0) || (f >= (u32)p); }
          if (__all(pred)) break;
        }
      }
      __syncthreads();
      stage8(h0ring + (p & (R0 - 1)) * HS, lds_h0, tid);                    // h0[p]
      if (p > 0) stage8(h1ring + ((p - 1) & (R1 - 1)) * HS, lds_h1, tid);   // h1[p-1]
      __syncthreads();
      if (tid == 0) stg4(prog + blk * 32, (u32)(p + 1));    // done reading h0[p]

      f32x4 a0 = bias, a1 = bias;
#pragma unroll
      for (int kc = 0; kc < 16; kc++) {
        short8 b0 = *(const short8*)(const void*)(lds_h0 + m * LROW + kc * 32 + q8);
        short8 b1 = *(const short8*)(const void*)(lds_h0 + (m + 16) * LROW + kc * 32 + q8);
        a0 = MFMA(A[kc], b0, a0);
        a1 = MFMA(A[kc], b1, a1);
      }
      if (p > 0) {
#pragma unroll
        for (int kc = 0; kc < 16; kc++) {
          short8 b0 = *(const short8*)(const void*)(lds_h1 + m * LROW + kc * 32 + q8);
          short8 b1 = *(const short8*)(const void*)(lds_h1 + (m + 16) * LROW + kc * 32 + q8);
          a0 = MFMA(A[16 + kc], b0, a0);
          a1 = MFMA(A[16 + kc], b1, a1);
        }
      }
      float ia = sigm(a0[0]), fa = sigm(a0[1]), ga = tanh_f(a0[2]), oa = sigm(a0[3]);
      c_a = fa * c_a + ia * ga;
      float ib = sigm(a1[0]), fb = sigm(a1[1]), gb = tanh_f(a1[2]), ob = sigm(a1[3]);
      c_b = fb * c_b + ib * gb;
      hpack[m * 16 + (w * 4 + q)]        = __float2bfloat16(oa * tanh_f(c_a));
      hpack[(m + 16) * 16 + (w * 4 + q)] = __float2bfloat16(ob * tanh_f(c_b));
      __syncthreads();
      if (w == 0) {
        u32x4 d = *(const u32x4*)(const void*)(hpack + lane * 8);
        stg16cv(h1ring + (p & (R1 - 1)) * HS + blk * 512 + lane * 8, d);
        asm volatile("s_waitcnt vmcnt(0)" ::: "memory");
        if (lane == 0) stg4(l1f + blk * 32, (u32)(p + 1));
      }
    }
  }
}

extern "C" void kernel_launch(void* const* d_in, const int* in_sizes, int n_in,
                              void* d_out, int out_size, void* d_ws, size_t ws_size,
                              hipStream_t stream) {
  const float* x    = (const float*)d_in[0];
  const float* Wih0 = (const float*)d_in[1];
  const float* Whh0 = (const float*)d_in[2];
  const float* bih0 = (const float*)d_in[3];
  const float* bhh0 = (const float*)d_in[4];
  const float* Wih1 = (const float*)d_in[5];
  const float* Whh1 = (const float*)d_in[6];
  const float* bih1 = (const float*)d_in[7];
  const float* bhh1 = (const float*)d_in[8];
  const float* fcw  = (const float*)d_in[9];
  const float* fcb  = (const float*)d_in[10];

  // ws: [0,4K) l0 flags; [4K,8K) l1 flags; [8K,12K) l1 progress; [16K,+256K) h0 ring;
  // then 128K h1 ring. Flags/progress must start at 0 (poisoned 0xAA otherwise).
  u32* l0f    = (u32*)d_ws;
  u32* l1f    = (u32*)((char*)d_ws + 4096);
  u32* prog   = (u32*)((char*)d_ws + 8192);
  bf16* h0ring = (bf16*)((char*)d_ws + 16384);
  bf16* h1ring = (bf16*)((char*)d_ws + 16384 + (size_t)R0 * HS * sizeof(bf16));

  hipMemsetAsync(d_ws, 0, 16384, stream);

  hipLaunchKernelGGL(lstm_persistent, dim3(NBLK), dim3(256), 0, stream,
                     x, Wih0, Whh0, bih0, bhh0, Wih1, Whh1, bih1, bhh1, fcw, fcb,
                     (float*)d_out, l0f, l1f, prog, h0ring, h1ring);
}